// Round 1
// baseline (1765.469 us; speedup 1.0000x reference)
//
#include <hip/hip_runtime.h>
#include <hip/hip_bf16.h>
#include <math.h>

// Problem dims
#define TI 128
#define NB 8
#define TO 32
#define TT 33      // TO+1
#define D 512
#define NH 8
#define HD 64
#define FF 2048
#define V 2000
#define NL 6
#define NTOK (TT*NB)   // 264 tokens, row = t*NB + n
#define MJ (NB*TI*TT)  // 33792 joiner rows, row = (n*TI+ti)*TT + t

typedef __attribute__((ext_vector_type(4))) float  f4;
typedef __attribute__((ext_vector_type(8))) short  shortx8;
typedef unsigned short u16;

__device__ __forceinline__ u16 f2bf(float f) {
    unsigned u = __float_as_uint(f);
    unsigned r = (u + 0x7fffu + ((u >> 16) & 1u)) >> 16;
    return (u16)r;
}
__device__ __forceinline__ float bf2f(u16 h) {
    return __uint_as_float(((unsigned)h) << 16);
}
__device__ __forceinline__ float wsum(float v) {
#pragma unroll
    for (int off = 32; off; off >>= 1) v += __shfl_xor(v, off, 64);
    return v;
}
__device__ __forceinline__ float wmax(float v) {
#pragma unroll
    for (int off = 32; off; off >>= 1) v = fmaxf(v, __shfl_xor(v, off, 64));
    return v;
}
__device__ __forceinline__ f4 mfma16(shortx8 a, shortx8 b, f4 c) {
    return __builtin_amdgcn_mfma_f32_16x16x32_bf16(a, b, c, 0, 0, 0);
}
__device__ __forceinline__ void async16(const void* g, void* l) {
    __builtin_amdgcn_global_load_lds(
        (const __attribute__((address_space(1))) unsigned int*)g,
        (__attribute__((address_space(3))) unsigned int*)l, 16, 0, 0);
}

// ---------------- embedding + positional encoding -------------------------
__global__ __launch_bounds__(256) void embed_kernel(
    const float* __restrict__ emb, const int* __restrict__ tgt_pad,
    const int* __restrict__ sos, float* __restrict__ x)
{
    int idx = blockIdx.x * 256 + threadIdx.x;
    if (idx >= NTOK * D) return;
    int d = idx & (D - 1);
    int row = idx >> 9;
    int t = row >> 3, n = row & 7;
    int tok = (t == 0) ? *sos : tgt_pad[n * TO + t - 1];
    float freq = __expf((float)(d & ~1) * (-0.017988946039015984f)); // -ln(10000)/512
    float ang = (float)t * freq;
    float pe = (d & 1) ? cosf(ang) : sinf(ang);
    x[idx] = emb[tok * D + d] * 22.627416997969522f + pe;
}

// ---------------- split-precision GEMM: C = A * B^T + bias ----------------
// A: M x K fp32 row-major, B: N x K fp32 row-major (weights), C: M x N fp32.
// fp32 inputs split to hi/lo bf16 during staging; 3 MFMAs per tile-product
// give ~2^-16 relative error (fp32-class).
template<int RELU>
__global__ __launch_bounds__(256) void gemm_split(
    const float* __restrict__ A, const float* __restrict__ B,
    const float* __restrict__ bias, float* __restrict__ C,
    int M, int N, int K)
{
    __shared__ u16 lsA[2 * 64 * 40];   // [plane][row][col], stride 40 pads banks
    __shared__ u16 lsB[2 * 64 * 40];
    const int tid = threadIdx.x;
    const int lane = tid & 63, w = tid >> 6;
    const int wr = (w >> 1) * 32, wc = (w & 1) * 32;
    const int m0 = blockIdx.x * 64, n0 = blockIdx.y * 64;
    const int qd = lane >> 4, mm = lane & 15;
    f4 acc[2][2] = {};

    for (int k0 = 0; k0 < K; k0 += 32) {
        __syncthreads();
#pragma unroll
        for (int i = 0; i < 2; ++i) {
            int idx = tid + i * 256;
            int row = idx >> 3;
            int c4 = (idx & 7) << 2;
            f4 va = {0.f, 0.f, 0.f, 0.f};
            int gr = m0 + row;
            if (gr < M) va = *(const f4*)(A + (size_t)gr * K + k0 + c4);
            f4 vb = {0.f, 0.f, 0.f, 0.f};
            int gn = n0 + row;
            if (gn < N) vb = *(const f4*)(B + (size_t)gn * K + k0 + c4);
            u16* pa = &lsA[row * 40 + c4];
            u16* pb = &lsB[row * 40 + c4];
#pragma unroll
            for (int j = 0; j < 4; ++j) {
                u16 h = f2bf(va[j]);
                pa[j] = h; pa[j + 2560] = f2bf(va[j] - bf2f(h));
                u16 g = f2bf(vb[j]);
                pb[j] = g; pb[j + 2560] = f2bf(vb[j] - bf2f(g));
            }
        }
        __syncthreads();
        shortx8 aH[2], aL[2], bH[2], bL[2];
#pragma unroll
        for (int rt = 0; rt < 2; ++rt) {
            const u16* p = &lsA[(wr + rt * 16 + mm) * 40 + qd * 8];
            aH[rt] = *(const shortx8*)p;
            aL[rt] = *(const shortx8*)(p + 2560);
            const u16* pb = &lsB[(wc + rt * 16 + mm) * 40 + qd * 8];
            bH[rt] = *(const shortx8*)pb;
            bL[rt] = *(const shortx8*)(pb + 2560);
        }
#pragma unroll
        for (int rt = 0; rt < 2; ++rt)
#pragma unroll
            for (int ct = 0; ct < 2; ++ct) {
                acc[rt][ct] = mfma16(aH[rt], bH[ct], acc[rt][ct]);
                acc[rt][ct] = mfma16(aH[rt], bL[ct], acc[rt][ct]);
                acc[rt][ct] = mfma16(aL[rt], bH[ct], acc[rt][ct]);
            }
    }
#pragma unroll
    for (int rt = 0; rt < 2; ++rt)
#pragma unroll
        for (int ct = 0; ct < 2; ++ct)
#pragma unroll
            for (int reg = 0; reg < 4; ++reg) {
                int grow = m0 + wr + rt * 16 + qd * 4 + reg;
                int gcol = n0 + wc + ct * 16 + mm;
                if (grow < M && gcol < N) {
                    float v = acc[rt][ct][reg] + bias[gcol];
                    if (RELU) v = fmaxf(v, 0.f);
                    C[(size_t)grow * N + gcol] = v;
                }
            }
}

// ---------------- attention (fp32, one block per (n,h)) -------------------
__global__ __launch_bounds__(256) void attn_kernel(
    const float* __restrict__ qkv, const int* __restrict__ tgt_len,
    float* __restrict__ o_attn)
{
    const int n = blockIdx.x >> 3, h = blockIdx.x & 7;
    const int tid = threadIdx.x, lane = tid & 63, w = tid >> 6;
    __shared__ float sq[TT * HD];   // [t][d]
    __shared__ float skT[HD * TT];  // [d][t]  (transposed: bank-friendly dot)
    __shared__ float sv[TT * HD];   // [t][d]
    for (int idx = tid; idx < TT * HD; idx += 256) {
        int t = idx >> 6, d = idx & 63;
        size_t base = (size_t)(t * NB + n) * (3 * D) + h * HD + d;
        sq[idx] = qkv[base] * 0.125f;          // 1/sqrt(64)
        skT[d * TT + t] = qkv[base + D];
        sv[idx] = qkv[base + 2 * D];
    }
    int len = max(tgt_len[n], 1);
    __syncthreads();
    for (int r = w; r < TT; r += 4) {
        bool ok = (lane < TT) && (lane <= r) && (lane < len);
        float s = -INFINITY;
        if (ok) {
            float dot = 0.f;
#pragma unroll 8
            for (int d = 0; d < HD; ++d) dot += sq[r * HD + d] * skT[d * TT + lane];
            s = dot;
        }
        float mx = wmax(s);
        float e = ok ? __expf(s - mx) : 0.f;
        float sum = wsum(e);
        float att = e / sum;
        float o = 0.f;
#pragma unroll
        for (int k = 0; k < TT; ++k) {
            float a = __shfl(att, k, 64);
            o += a * sv[k * HD + lane];
        }
        o_attn[(size_t)(r * NB + n) * D + h * HD + lane] = o;
    }
}

// ---------------- residual add + LayerNorm (one wave per row) -------------
__global__ __launch_bounds__(256) void add_ln(
    float* __restrict__ x, const float* __restrict__ r,
    const float* __restrict__ s, const float* __restrict__ b)
{
    int row = blockIdx.x * 4 + (threadIdx.x >> 6);
    int lane = threadIdx.x & 63;
    if (row >= NTOK) return;
    float* xr = x + (size_t)row * D;
    const float* rr = r + (size_t)row * D;
    f4 v1 = *(const f4*)(xr + lane * 4);
    f4 v2 = *(const f4*)(xr + 256 + lane * 4);
    v1 += *(const f4*)(rr + lane * 4);
    v2 += *(const f4*)(rr + 256 + lane * 4);
    float sum = 0.f, sq = 0.f;
#pragma unroll
    for (int j = 0; j < 4; ++j) {
        sum += v1[j] + v2[j];
        sq += v1[j] * v1[j] + v2[j] * v2[j];
    }
    sum = wsum(sum); sq = wsum(sq);
    float mean = sum * (1.f / D);
    float var = sq * (1.f / D) - mean * mean;
    float rstd = rsqrtf(var + 1e-5f);
    f4 o1, o2;
#pragma unroll
    for (int j = 0; j < 4; ++j) {
        int c1 = lane * 4 + j, c2 = c1 + 256;
        o1[j] = (v1[j] - mean) * rstd * s[c1] + b[c1];
        o2[j] = (v2[j] - mean) * rstd * s[c2] + b[c2];
    }
    *(f4*)(xr + lane * 4) = o1;
    *(f4*)(xr + 256 + lane * 4) = o2;
}

// ---------------- joiner prep: A = bf16(tanh(enc + x)), B = bf16(out_w) ---
__global__ __launch_bounds__(256) void prep_joiner_A(
    const float* __restrict__ encb, const float* __restrict__ x,
    u16* __restrict__ Aj)
{
    int idx = blockIdx.x * 256 + threadIdx.x;       // one per 8 elems
    int d8 = (idx & 63) << 3;
    int row = idx >> 6;                              // (n*TI+ti)*TT + t
    int n = row / (TI * TT);
    int rem = row - n * (TI * TT);
    int ti = rem / TT;
    int t = rem - ti * TT;
    const float* pe = encb + (size_t)(ti * NB + n) * D + d8;
    const float* px = x + (size_t)(t * NB + n) * D + d8;
    f4 e0 = *(const f4*)pe, e1 = *(const f4*)(pe + 4);
    f4 x0 = *(const f4*)px, x1 = *(const f4*)(px + 4);
    u16* dst = Aj + (size_t)row * D + d8;
#pragma unroll
    for (int j = 0; j < 4; ++j) {
        dst[j] = f2bf(tanhf(e0[j] + x0[j]));
        dst[4 + j] = f2bf(tanhf(e1[j] + x1[j]));
    }
}

__global__ __launch_bounds__(256) void prep_joiner_B(
    const float* __restrict__ out_w, u16* __restrict__ Bj)
{
    int idx = blockIdx.x * 256 + threadIdx.x;       // one per 8 elems, 2048x512
    int d8 = (idx & 63) << 3;
    int row = idx >> 6;
    u16* dst = Bj + (size_t)row * D + d8;
    if (row < V) {
        const float* p = out_w + (size_t)row * D + d8;
        f4 a = *(const f4*)p, b = *(const f4*)(p + 4);
#pragma unroll
        for (int j = 0; j < 4; ++j) { dst[j] = f2bf(a[j]); dst[4 + j] = f2bf(b[j]); }
    } else {
#pragma unroll
        for (int j = 0; j < 8; ++j) dst[j] = 0;
    }
}

// ---------------- joiner GEMM: out[MJ x 2000] = Aj * Bj^T (bf16 MFMA) -----
// 128x128 tile, BK=32, global_load_lds width 16, XOR chunk swizzle so the
// ds_read_b128 fragment reads land at free 2-way bank conflicts.
__global__ __launch_bounds__(256) void joiner_gemm(
    const u16* __restrict__ Aj, const u16* __restrict__ Bj,
    float* __restrict__ out)
{
    __shared__ u16 lsA[128 * 32];
    __shared__ u16 lsB[128 * 32];
    const int bid = blockIdx.x;
    const int mt = bid >> 4, nt = bid & 15;
    const int tid = threadIdx.x, lane = tid & 63, w = tid >> 6;
    const int wr = (w >> 1) * 64, wc = (w & 1) * 64;
    const int qd = lane >> 4, mm = lane & 15;
    f4 acc[4][4] = {};
    const u16* Abase = Aj + (size_t)mt * 128 * D;
    const u16* Bbase = Bj + (size_t)nt * 128 * D;

    for (int k0 = 0; k0 < D; k0 += 32) {
        __syncthreads();
#pragma unroll
        for (int i = 0; i < 2; ++i) {
            int idx = tid + i * 256;
            int row = idx >> 2, c = idx & 3;
            int chunk = c ^ ((row >> 1) & 3);
            async16(Abase + (size_t)row * D + k0 + chunk * 8, lsA + idx * 8);
            async16(Bbase + (size_t)row * D + k0 + chunk * 8, lsB + idx * 8);
        }
        __syncthreads();
        shortx8 af[4], bf[4];
#pragma unroll
        for (int rt = 0; rt < 4; ++rt) {
            int row = wr + rt * 16 + mm;
            int cpos = qd ^ ((row >> 1) & 3);
            af[rt] = *(const shortx8*)(lsA + row * 32 + cpos * 8);
        }
#pragma unroll
        for (int ct = 0; ct < 4; ++ct) {
            int col = wc + ct * 16 + mm;
            int cpos = qd ^ ((col >> 1) & 3);
            bf[ct] = *(const shortx8*)(lsB + col * 32 + cpos * 8);
        }
#pragma unroll
        for (int rt = 0; rt < 4; ++rt)
#pragma unroll
            for (int ct = 0; ct < 4; ++ct)
                acc[rt][ct] = mfma16(af[rt], bf[ct], acc[rt][ct]);
    }
#pragma unroll
    for (int rt = 0; rt < 4; ++rt)
#pragma unroll
        for (int ct = 0; ct < 4; ++ct)
#pragma unroll
            for (int reg = 0; reg < 4; ++reg) {
                int grow = mt * 128 + wr + rt * 16 + qd * 4 + reg;
                int gcol = nt * 128 + wc + ct * 16 + mm;
                if (gcol < V) out[(size_t)grow * V + gcol] = acc[rt][ct][reg];
            }
}

// --------------------------------------------------------------------------
extern "C" void kernel_launch(void* const* d_in, const int* in_sizes, int n_in,
                              void* d_out, int out_size, void* d_ws, size_t ws_size,
                              hipStream_t stream)
{
    const float* enc_out = (const float*)d_in[0];
    const float* embed_w = (const float*)d_in[1];
    const float* enc_w   = (const float*)d_in[2];
    const float* enc_b   = (const float*)d_in[3];
    const float* qkv_w   = (const float*)d_in[4];
    const float* qkv_b   = (const float*)d_in[5];
    const float* o_w     = (const float*)d_in[6];
    const float* o_b     = (const float*)d_in[7];
    const float* ln1_s   = (const float*)d_in[8];
    const float* ln1_b   = (const float*)d_in[9];
    const float* ff1_w   = (const float*)d_in[10];
    const float* ff1_b   = (const float*)d_in[11];
    const float* ff2_w   = (const float*)d_in[12];
    const float* ff2_b   = (const float*)d_in[13];
    const float* ln2_s   = (const float*)d_in[14];
    const float* ln2_b   = (const float*)d_in[15];
    const float* out_w   = (const float*)d_in[16];
    const int*   tgt_pad = (const int*)d_in[17];
    const int*   tgt_len = (const int*)d_in[18];
    const int*   sos     = (const int*)d_in[19];

    float* ws   = (float*)d_ws;
    float* x      = ws;                 // 264*512
    float* qkv    = ws + 135168;        // 264*1536
    float* o_attn = ws + 540672;        // 264*512
    float* tmp    = ws + 675840;        // 264*512
    float* h      = ws + 811008;        // 264*2048
    float* encb   = ws + 1351680;       // 1024*512
    u16* Aj = (u16*)(ws + 1875968);     // 33792*512 bf16
    u16* Bj = Aj + (size_t)MJ * D;      // 2048*512 bf16

    embed_kernel<<<528, 256, 0, stream>>>(embed_w, tgt_pad, sos, x);
    for (int l = 0; l < NL; ++l) {
        gemm_split<0><<<dim3(5, 24), 256, 0, stream>>>(
            x, qkv_w + (size_t)l * 3 * D * D, qkv_b + l * 3 * D, qkv, NTOK, 3 * D, D);
        attn_kernel<<<NB * NH, 256, 0, stream>>>(qkv, tgt_len, o_attn);
        gemm_split<0><<<dim3(5, 8), 256, 0, stream>>>(
            o_attn, o_w + (size_t)l * D * D, o_b + l * D, tmp, NTOK, D, D);
        add_ln<<<66, 256, 0, stream>>>(x, tmp, ln1_s + l * D, ln1_b + l * D);
        gemm_split<1><<<dim3(5, 32), 256, 0, stream>>>(
            x, ff1_w + (size_t)l * FF * D, ff1_b + l * FF, h, NTOK, FF, D);
        gemm_split<0><<<dim3(5, 8), 256, 0, stream>>>(
            h, ff2_w + (size_t)l * D * FF, ff2_b + l * D, tmp, NTOK, D, FF);
        add_ln<<<66, 256, 0, stream>>>(x, tmp, ln2_s + l * D, ln2_b + l * D);
    }
    gemm_split<0><<<dim3(16, 8), 256, 0, stream>>>(
        enc_out, enc_w, enc_b, encb, TI * NB, D, D);
    prep_joiner_A<<<(MJ * D / 8) / 256, 256, 0, stream>>>(encb, x, Aj);
    prep_joiner_B<<<(2048 * D / 8) / 256, 256, 0, stream>>>(out_w, Bj);
    joiner_gemm<<<264 * 16, 256, 0, stream>>>(Aj, Bj, (float*)d_out);
}

// Round 2
// 974.234 us; speedup vs baseline: 1.8122x; 1.8122x over previous
//
#include <hip/hip_runtime.h>
#include <hip/hip_bf16.h>
#include <math.h>

// Problem dims
#define TI 128
#define NB 8
#define TO 32
#define TT 33      // TO+1
#define D 512
#define NH 8
#define HD 64
#define FF 2048
#define V 2000
#define NL 6
#define NTOK (TT*NB)   // 264 tokens, row = t*NB + n
#define MJ (NB*TI*TT)  // 33792 joiner rows, row = (n*TI+ti)*TT + t

typedef __attribute__((ext_vector_type(4))) float  f4;
typedef __attribute__((ext_vector_type(8))) short  shortx8;
typedef unsigned short u16;

__device__ __forceinline__ u16 f2bf(float f) {
    unsigned u = __float_as_uint(f);
    unsigned r = (u + 0x7fffu + ((u >> 16) & 1u)) >> 16;
    return (u16)r;
}
__device__ __forceinline__ float bf2f(u16 h) {
    return __uint_as_float(((unsigned)h) << 16);
}
__device__ __forceinline__ float wsum(float v) {
#pragma unroll
    for (int off = 32; off; off >>= 1) v += __shfl_xor(v, off, 64);
    return v;
}
__device__ __forceinline__ float wmax(float v) {
#pragma unroll
    for (int off = 32; off; off >>= 1) v = fmaxf(v, __shfl_xor(v, off, 64));
    return v;
}
__device__ __forceinline__ f4 mfma16(shortx8 a, shortx8 b, f4 c) {
    return __builtin_amdgcn_mfma_f32_16x16x32_bf16(a, b, c, 0, 0, 0);
}
__device__ __forceinline__ void async16(const void* g, void* l) {
    __builtin_amdgcn_global_load_lds(
        (const __attribute__((address_space(1))) unsigned int*)g,
        (__attribute__((address_space(3))) unsigned int*)l, 16, 0, 0);
}

// ---------------- weight pre-split: fp32 -> bf16 hi/lo planes -------------
// segments (f4 units): qkv 1179648 | o 393216 | ff1 1572864 | ff2 1572864 | enc 65536
__global__ __launch_bounds__(256) void convert_w(
    const float* __restrict__ q, const float* __restrict__ o,
    const float* __restrict__ f1, const float* __restrict__ f2,
    const float* __restrict__ e, u16* __restrict__ Wh, u16* __restrict__ Wl)
{
    int i4 = blockIdx.x * 256 + threadIdx.x;   // 4784128 total
    const float* src; int loc;
    if (i4 < 1179648)      { src = q;  loc = i4; }
    else if (i4 < 1572864) { src = o;  loc = i4 - 1179648; }
    else if (i4 < 3145728) { src = f1; loc = i4 - 1572864; }
    else if (i4 < 4718592) { src = f2; loc = i4 - 3145728; }
    else                   { src = e;  loc = i4 - 4718592; }
    f4 v = *(const f4*)(src + (size_t)loc * 4);
    ushort4 h, l;
    h.x = f2bf(v[0]); l.x = f2bf(v[0] - bf2f(h.x));
    h.y = f2bf(v[1]); l.y = f2bf(v[1] - bf2f(h.y));
    h.z = f2bf(v[2]); l.z = f2bf(v[2] - bf2f(h.z));
    h.w = f2bf(v[3]); l.w = f2bf(v[3] - bf2f(h.w));
    *(ushort4*)(Wh + (size_t)i4 * 4) = h;
    *(ushort4*)(Wl + (size_t)i4 * 4) = l;
}

__global__ __launch_bounds__(256) void convert_plane(
    const float* __restrict__ src, u16* __restrict__ dh, u16* __restrict__ dl, int n4)
{
    int i = blockIdx.x * 256 + threadIdx.x;
    if (i >= n4) return;
    f4 v = *(const f4*)(src + (size_t)i * 4);
    ushort4 h, l;
    h.x = f2bf(v[0]); l.x = f2bf(v[0] - bf2f(h.x));
    h.y = f2bf(v[1]); l.y = f2bf(v[1] - bf2f(h.y));
    h.z = f2bf(v[2]); l.z = f2bf(v[2] - bf2f(h.z));
    h.w = f2bf(v[3]); l.w = f2bf(v[3] - bf2f(h.w));
    *(ushort4*)(dh + (size_t)i * 4) = h;
    *(ushort4*)(dl + (size_t)i * 4) = l;
}

// ---------------- embedding + positional encoding -------------------------
__global__ __launch_bounds__(256) void embed_kernel(
    const float* __restrict__ emb, const int* __restrict__ tgt_pad,
    const int* __restrict__ sos, float* __restrict__ x,
    u16* __restrict__ xh, u16* __restrict__ xl)
{
    int idx = blockIdx.x * 256 + threadIdx.x;
    if (idx >= NTOK * D) return;
    int d = idx & (D - 1);
    int row = idx >> 9;
    int t = row >> 3, n = row & 7;
    int tok = (t == 0) ? *sos : tgt_pad[n * TO + t - 1];
    float freq = __expf((float)(d & ~1) * (-0.017988946039015984f)); // -ln(10000)/512
    float ang = (float)t * freq;
    float pe = (d & 1) ? cosf(ang) : sinf(ang);
    float v = emb[tok * D + d] * 22.627416997969522f + pe;
    x[idx] = v;
    u16 h = f2bf(v);
    xh[idx] = h;
    xl[idx] = f2bf(v - bf2f(h));
}

// ---------------- bf16 hi/lo GEMM: C = A * B^T (+bias) --------------------
// A: hi/lo planes [Mpad][lda], B: hi/lo planes [N][ldb]. 64x64 tile, BK=64,
// global_load_lds width-16 staging, 3-product split MFMA (~fp32 accuracy).
// MODE 0: fp32 out + bias. MODE 1: fp32 split-K partial (blockIdx.z = k-slice),
// no bias, C offset z*M*ldc. MODE 2: bf16 hi/lo out + bias + relu.
template<int MODE>
__global__ __launch_bounds__(256) void gemm_bf(
    const u16* __restrict__ Ah, const u16* __restrict__ Al, int lda,
    const u16* __restrict__ Bh, const u16* __restrict__ Bl, int ldb,
    const float* __restrict__ bias,
    float* __restrict__ C, u16* __restrict__ Ch, u16* __restrict__ Cl,
    int M, int N, int ldc, int ksteps)
{
    __shared__ u16 ls[4][64 * 64];   // Ah, Al, Bh, Bl tiles
    const int tid = threadIdx.x, lane = tid & 63, w = tid >> 6;
    const int wr = (w >> 1) * 32, wc = (w & 1) * 32;
    const int m0 = blockIdx.x * 64, n0 = blockIdx.y * 64;
    const int qd = lane >> 4, mm = lane & 15;
    const int kb = (MODE == 1) ? (int)blockIdx.z * ksteps * 64 : 0;
    f4 acc[2][2] = {};
    const u16* Ab  = Ah + (size_t)m0 * lda + kb;
    const u16* Alb = Al + (size_t)m0 * lda + kb;
    const u16* Bb  = Bh + (size_t)n0 * ldb + kb;
    const u16* Blb = Bl + (size_t)n0 * ldb + kb;

    for (int it = 0; it < ksteps; ++it) {
        int k0 = it * 64;
        __syncthreads();
#pragma unroll
        for (int i = 0; i < 2; ++i) {
            int idx = tid + i * 256;
            int row = idx >> 3, c8 = (idx & 7) * 8;
            async16(Ab  + (size_t)row * lda + k0 + c8, &ls[0][idx * 8]);
            async16(Alb + (size_t)row * lda + k0 + c8, &ls[1][idx * 8]);
            async16(Bb  + (size_t)row * ldb + k0 + c8, &ls[2][idx * 8]);
            async16(Blb + (size_t)row * ldb + k0 + c8, &ls[3][idx * 8]);
        }
        __syncthreads();
#pragma unroll
        for (int kk = 0; kk < 2; ++kk) {
            shortx8 aH[2], aL[2], bH[2], bL[2];
#pragma unroll
            for (int rt = 0; rt < 2; ++rt) {
                int row = wr + rt * 16 + mm;
                aH[rt] = *(const shortx8*)&ls[0][row * 64 + kk * 32 + qd * 8];
                aL[rt] = *(const shortx8*)&ls[1][row * 64 + kk * 32 + qd * 8];
                int col = wc + rt * 16 + mm;
                bH[rt] = *(const shortx8*)&ls[2][col * 64 + kk * 32 + qd * 8];
                bL[rt] = *(const shortx8*)&ls[3][col * 64 + kk * 32 + qd * 8];
            }
#pragma unroll
            for (int rt = 0; rt < 2; ++rt)
#pragma unroll
                for (int ct = 0; ct < 2; ++ct) {
                    acc[rt][ct] = mfma16(aH[rt], bH[ct], acc[rt][ct]);
                    acc[rt][ct] = mfma16(aH[rt], bL[ct], acc[rt][ct]);
                    acc[rt][ct] = mfma16(aL[rt], bH[ct], acc[rt][ct]);
                }
        }
    }
    float* Cz = C;
    if (MODE == 1) Cz = C + (size_t)blockIdx.z * (size_t)M * ldc;
#pragma unroll
    for (int rt = 0; rt < 2; ++rt)
#pragma unroll
        for (int ct = 0; ct < 2; ++ct)
#pragma unroll
            for (int reg = 0; reg < 4; ++reg) {
                int grow = m0 + wr + rt * 16 + qd * 4 + reg;
                int gcol = n0 + wc + ct * 16 + mm;
                if (grow < M) {
                    float v = acc[rt][ct][reg];
                    if (MODE != 1) v += bias[gcol];
                    if (MODE == 2) {
                        v = fmaxf(v, 0.f);
                        u16 h = f2bf(v);
                        Ch[(size_t)grow * ldc + gcol] = h;
                        Cl[(size_t)grow * ldc + gcol] = f2bf(v - bf2f(h));
                    } else {
                        Cz[(size_t)grow * ldc + gcol] = v;
                    }
                }
            }
}

// ---------------- attention (fp32, one block per (n,h)) -------------------
__global__ __launch_bounds__(256) void attn_kernel(
    const float* __restrict__ qkv, const int* __restrict__ tgt_len,
    u16* __restrict__ oh, u16* __restrict__ ol)
{
    const int n = blockIdx.x >> 3, h = blockIdx.x & 7;
    const int tid = threadIdx.x, lane = tid & 63, w = tid >> 6;
    __shared__ float sq[TT * HD];   // [t][d]
    __shared__ float skT[HD * TT];  // [d][t]
    __shared__ float sv[TT * HD];   // [t][d]
    for (int idx = tid; idx < TT * HD; idx += 256) {
        int t = idx >> 6, d = idx & 63;
        size_t base = (size_t)(t * NB + n) * (3 * D) + h * HD + d;
        sq[idx] = qkv[base] * 0.125f;          // 1/sqrt(64)
        skT[d * TT + t] = qkv[base + D];
        sv[idx] = qkv[base + 2 * D];
    }
    int len = max(tgt_len[n], 1);
    __syncthreads();
    for (int r = w; r < TT; r += 4) {
        bool ok = (lane < TT) && (lane <= r) && (lane < len);
        float s = -INFINITY;
        if (ok) {
            float dot = 0.f;
#pragma unroll 8
            for (int d = 0; d < HD; ++d) dot += sq[r * HD + d] * skT[d * TT + lane];
            s = dot;
        }
        float mx = wmax(s);
        float e = ok ? __expf(s - mx) : 0.f;
        float sum = wsum(e);
        float att = e / sum;
        float o = 0.f;
#pragma unroll
        for (int k = 0; k < TT; ++k) {
            float a = __shfl(att, k, 64);
            o += a * sv[k * HD + lane];
        }
        size_t oi = (size_t)(r * NB + n) * D + h * HD + lane;
        u16 hh = f2bf(o);
        oh[oi] = hh;
        ol[oi] = f2bf(o - bf2f(hh));
    }
}

// ---------------- residual add (+NP partials) + LayerNorm -----------------
// Writes x fp32 and its bf16 hi/lo planes.
template<int NP, int BIAS>
__global__ __launch_bounds__(256) void add_ln(
    float* __restrict__ x, const float* __restrict__ r,
    const float* __restrict__ bias2,
    const float* __restrict__ s, const float* __restrict__ b,
    u16* __restrict__ xh, u16* __restrict__ xl)
{
    int row = blockIdx.x * 4 + (threadIdx.x >> 6);
    int lane = threadIdx.x & 63;
    if (row >= NTOK) return;
    float* xr = x + (size_t)row * D;
    f4 v1 = *(const f4*)(xr + lane * 4);
    f4 v2 = *(const f4*)(xr + 256 + lane * 4);
#pragma unroll
    for (int p = 0; p < NP; ++p) {
        const float* rr = r + (size_t)p * (NTOK * D) + (size_t)row * D;
        v1 += *(const f4*)(rr + lane * 4);
        v2 += *(const f4*)(rr + 256 + lane * 4);
    }
    if (BIAS) {
        v1 += *(const f4*)(bias2 + lane * 4);
        v2 += *(const f4*)(bias2 + 256 + lane * 4);
    }
    float sum = 0.f, sq = 0.f;
#pragma unroll
    for (int j = 0; j < 4; ++j) {
        sum += v1[j] + v2[j];
        sq += v1[j] * v1[j] + v2[j] * v2[j];
    }
    sum = wsum(sum); sq = wsum(sq);
    float mean = sum * (1.f / D);
    float var = sq * (1.f / D) - mean * mean;
    float rstd = rsqrtf(var + 1e-5f);
    f4 o1, o2;
    ushort4 h1, l1, h2, l2;
    u16 th, tl;
#pragma unroll
    for (int j = 0; j < 4; ++j) {
        int c1 = lane * 4 + j, c2 = c1 + 256;
        o1[j] = (v1[j] - mean) * rstd * s[c1] + b[c1];
        o2[j] = (v2[j] - mean) * rstd * s[c2] + b[c2];
    }
    th = f2bf(o1[0]); tl = f2bf(o1[0] - bf2f(th)); h1.x = th; l1.x = tl;
    th = f2bf(o1[1]); tl = f2bf(o1[1] - bf2f(th)); h1.y = th; l1.y = tl;
    th = f2bf(o1[2]); tl = f2bf(o1[2] - bf2f(th)); h1.z = th; l1.z = tl;
    th = f2bf(o1[3]); tl = f2bf(o1[3] - bf2f(th)); h1.w = th; l1.w = tl;
    th = f2bf(o2[0]); tl = f2bf(o2[0] - bf2f(th)); h2.x = th; l2.x = tl;
    th = f2bf(o2[1]); tl = f2bf(o2[1] - bf2f(th)); h2.y = th; l2.y = tl;
    th = f2bf(o2[2]); tl = f2bf(o2[2] - bf2f(th)); h2.z = th; l2.z = tl;
    th = f2bf(o2[3]); tl = f2bf(o2[3] - bf2f(th)); h2.w = th; l2.w = tl;
    *(f4*)(xr + lane * 4) = o1;
    *(f4*)(xr + 256 + lane * 4) = o2;
    *(ushort4*)(xh + (size_t)row * D + lane * 4) = h1;
    *(ushort4*)(xl + (size_t)row * D + lane * 4) = l1;
    *(ushort4*)(xh + (size_t)row * D + 256 + lane * 4) = h2;
    *(ushort4*)(xl + (size_t)row * D + 256 + lane * 4) = l2;
}

// ---------------- joiner prep: A = bf16(tanh(enc + x)), B = bf16(out_w) ---
__global__ __launch_bounds__(256) void prep_joiner_A(
    const float* __restrict__ encb, const float* __restrict__ x,
    u16* __restrict__ Aj)
{
    int idx = blockIdx.x * 256 + threadIdx.x;       // one per 8 elems
    int d8 = (idx & 63) << 3;
    int row = idx >> 6;                              // (n*TI+ti)*TT + t
    int n = row / (TI * TT);
    int rem = row - n * (TI * TT);
    int ti = rem / TT;
    int t = rem - ti * TT;
    const float* pe = encb + (size_t)(ti * NB + n) * D + d8;
    const float* px = x + (size_t)(t * NB + n) * D + d8;
    f4 e0 = *(const f4*)pe, e1 = *(const f4*)(pe + 4);
    f4 x0 = *(const f4*)px, x1 = *(const f4*)(px + 4);
    u16* dst = Aj + (size_t)row * D + d8;
#pragma unroll
    for (int j = 0; j < 4; ++j) {
        dst[j] = f2bf(tanhf(e0[j] + x0[j]));
        dst[4 + j] = f2bf(tanhf(e1[j] + x1[j]));
    }
}

__global__ __launch_bounds__(256) void prep_joiner_B(
    const float* __restrict__ out_w, u16* __restrict__ Bj)
{
    int idx = blockIdx.x * 256 + threadIdx.x;       // one per 8 elems, 2048x512
    int d8 = (idx & 63) << 3;
    int row = idx >> 6;
    u16* dst = Bj + (size_t)row * D + d8;
    if (row < V) {
        const float* p = out_w + (size_t)row * D + d8;
        f4 a = *(const f4*)p, b = *(const f4*)(p + 4);
#pragma unroll
        for (int j = 0; j < 4; ++j) { dst[j] = f2bf(a[j]); dst[4 + j] = f2bf(b[j]); }
    } else {
#pragma unroll
        for (int j = 0; j < 8; ++j) dst[j] = 0;
    }
}

// ---------------- joiner GEMM: out[MJ x 2000] = Aj * Bj^T (bf16 MFMA) -----
__global__ __launch_bounds__(256) void joiner_gemm(
    const u16* __restrict__ Aj, const u16* __restrict__ Bj,
    float* __restrict__ out)
{
    __shared__ u16 lsA[128 * 32];
    __shared__ u16 lsB[128 * 32];
    const int bid = blockIdx.x;
    const int mt = bid >> 4, nt = bid & 15;
    const int tid = threadIdx.x, lane = tid & 63, w = tid >> 6;
    const int wr = (w >> 1) * 64, wc = (w & 1) * 64;
    const int qd = lane >> 4, mm = lane & 15;
    f4 acc[4][4] = {};
    const u16* Abase = Aj + (size_t)mt * 128 * D;
    const u16* Bbase = Bj + (size_t)nt * 128 * D;

    for (int k0 = 0; k0 < D; k0 += 32) {
        __syncthreads();
#pragma unroll
        for (int i = 0; i < 2; ++i) {
            int idx = tid + i * 256;
            int row = idx >> 2, c = idx & 3;
            int chunk = c ^ ((row >> 1) & 3);
            async16(Abase + (size_t)row * D + k0 + chunk * 8, lsA + idx * 8);
            async16(Bbase + (size_t)row * D + k0 + chunk * 8, lsB + idx * 8);
        }
        __syncthreads();
        shortx8 af[4], bf[4];
#pragma unroll
        for (int rt = 0; rt < 4; ++rt) {
            int row = wr + rt * 16 + mm;
            int cpos = qd ^ ((row >> 1) & 3);
            af[rt] = *(const shortx8*)(lsA + row * 32 + cpos * 8);
        }
#pragma unroll
        for (int ct = 0; ct < 4; ++ct) {
            int col = wc + ct * 16 + mm;
            int cpos = qd ^ ((col >> 1) & 3);
            bf[ct] = *(const shortx8*)(lsB + col * 32 + cpos * 8);
        }
#pragma unroll
        for (int rt = 0; rt < 4; ++rt)
#pragma unroll
            for (int ct = 0; ct < 4; ++ct)
                acc[rt][ct] = mfma16(af[rt], bf[ct], acc[rt][ct]);
    }
#pragma unroll
    for (int rt = 0; rt < 4; ++rt)
#pragma unroll
        for (int ct = 0; ct < 4; ++ct)
#pragma unroll
            for (int reg = 0; reg < 4; ++reg) {
                int grow = mt * 128 + wr + rt * 16 + qd * 4 + reg;
                int gcol = nt * 128 + wc + ct * 16 + mm;
                if (gcol < V) out[(size_t)grow * V + gcol] = acc[rt][ct][reg];
            }
}

// --------------------------------------------------------------------------
extern "C" void kernel_launch(void* const* d_in, const int* in_sizes, int n_in,
                              void* d_out, int out_size, void* d_ws, size_t ws_size,
                              hipStream_t stream)
{
    const float* enc_out = (const float*)d_in[0];
    const float* embed_w = (const float*)d_in[1];
    const float* enc_w   = (const float*)d_in[2];
    const float* enc_b   = (const float*)d_in[3];
    const float* qkv_w   = (const float*)d_in[4];
    const float* qkv_b   = (const float*)d_in[5];
    const float* o_w     = (const float*)d_in[6];
    const float* o_b     = (const float*)d_in[7];
    const float* ln1_s   = (const float*)d_in[8];
    const float* ln1_b   = (const float*)d_in[9];
    const float* ff1_w   = (const float*)d_in[10];
    const float* ff1_b   = (const float*)d_in[11];
    const float* ff2_w   = (const float*)d_in[12];
    const float* ff2_b   = (const float*)d_in[13];
    const float* ln2_s   = (const float*)d_in[14];
    const float* ln2_b   = (const float*)d_in[15];
    const float* out_w   = (const float*)d_in[16];
    const int*   tgt_pad = (const int*)d_in[17];
    const int*   tgt_len = (const int*)d_in[18];
    const int*   sos     = (const int*)d_in[19];

    float* ws = (float*)d_ws;
    float* x    = ws;                  // 264x512 = 135168 f
    float* qkvb = ws + 135168;         // 264x1536 = 405504 f
    float* tmp  = ws + 540672;         // 264x512
    float* part = ws + 675840;         // 4x264x512 = 540672 f
    float* encb = ws + 1216512;        // 1024x512 = 524288 f
    u16* u  = (u16*)(ws + 1740800);
    u16* xh = u;                  u16* xl = xh + 320 * 512;     // padded to 320 rows
    u16* oh = xl + 163840;        u16* ol = oh + 163840;
    u16* hh = ol + 163840;        u16* hl = hh + 320 * 2048;    // 655360 each
    u16* eh = hl + 655360;        u16* el = eh + 524288;        // 1024x512
    u16* Wh = el + 524288;        u16* Wl = Wh + 19136512;
    u16* Aj = Wl + 19136512;      u16* Bj = Aj + (size_t)MJ * D;

    // weight plane element offsets inside Wh/Wl
    const size_t QO = 0;              // + l*786432   (1536x512)
    const size_t OO = 4718592;        // + l*262144   (512x512)
    const size_t F1 = 6291456;        // + l*1048576  (2048x512)
    const size_t F2 = 12582912;       // + l*1048576  (512x2048)
    const size_t EW = 18874368;       // 512x512

    convert_w<<<18688, 256, 0, stream>>>(qkv_w, o_w, ff1_w, ff2_w, enc_w, Wh, Wl);
    convert_plane<<<512, 256, 0, stream>>>(enc_out, eh, el, 131072);
    embed_kernel<<<528, 256, 0, stream>>>(embed_w, tgt_pad, sos, x, xh, xl);
    for (int l = 0; l < NL; ++l) {
        gemm_bf<0><<<dim3(5, 24), 256, 0, stream>>>(
            xh, xl, 512, Wh + QO + (size_t)l * 786432, Wl + QO + (size_t)l * 786432, 512,
            qkv_b + l * 1536, qkvb, nullptr, nullptr, NTOK, 1536, 1536, 8);
        attn_kernel<<<NB * NH, 256, 0, stream>>>(qkvb, tgt_len, oh, ol);
        gemm_bf<0><<<dim3(5, 8), 256, 0, stream>>>(
            oh, ol, 512, Wh + OO + (size_t)l * 262144, Wl + OO + (size_t)l * 262144, 512,
            o_b + l * 512, tmp, nullptr, nullptr, NTOK, 512, 512, 8);
        add_ln<1, 0><<<66, 256, 0, stream>>>(
            x, tmp, nullptr, ln1_s + l * 512, ln1_b + l * 512, xh, xl);
        gemm_bf<2><<<dim3(5, 32), 256, 0, stream>>>(
            xh, xl, 512, Wh + F1 + (size_t)l * 1048576, Wl + F1 + (size_t)l * 1048576, 512,
            ff1_b + l * 2048, nullptr, hh, hl, NTOK, 2048, 2048, 8);
        gemm_bf<1><<<dim3(5, 8, 4), 256, 0, stream>>>(
            hh, hl, 2048, Wh + F2 + (size_t)l * 1048576, Wl + F2 + (size_t)l * 1048576, 2048,
            nullptr, part, nullptr, nullptr, NTOK, 512, 512, 8);
        add_ln<4, 1><<<66, 256, 0, stream>>>(
            x, part, ff2_b + l * 512, ln2_s + l * 512, ln2_b + l * 512, xh, xl);
    }
    gemm_bf<0><<<dim3(16, 8), 256, 0, stream>>>(
        eh, el, 512, Wh + EW, Wl + EW, 512,
        enc_b, encb, nullptr, nullptr, TI * NB, 512, 512, 8);
    prep_joiner_A<<<(MJ * D / 8) / 256, 256, 0, stream>>>(encb, x, Aj);
    prep_joiner_B<<<(2048 * D / 8) / 256, 256, 0, stream>>>(out_w, Bj);
    joiner_gemm<<<264 * 16, 256, 0, stream>>>(Aj, Bj, (float*)d_out);
}